// Round 4
// baseline (615.935 us; speedup 1.0000x reference)
//
#include <hip/hip_runtime.h>
#include <stdint.h>

// Problem constants
#define NB 4096
#define NT 512
#define OT 513
#define TOTE (NB*OT)          // 2101248 elements per output matrix
#define LOSSOFF (2*TOTE)      // diff_loss slot

typedef float  f32x4 __attribute__((ext_vector_type(4)));
typedef __fp16 f16x8 __attribute__((ext_vector_type(8)));
typedef __fp16 f16x2 __attribute__((ext_vector_type(2)));

#define MFMA(A,B,C) __builtin_amdgcn_mfma_f32_16x16x32_f16((A),(B),(C),0,0,0)

// Barrier that drains LDS only (no vmcnt(0) drain -> global stores stay in flight)
__device__ __forceinline__ void wg_barrier() {
  asm volatile("s_waitcnt lgkmcnt(0)\n\ts_barrier" ::: "memory");
}

__device__ __forceinline__ float fast_tanh(float x) {
  float e = __builtin_amdgcn_exp2f(x * 2.8853900817779268f); // 2*log2(e)
  return __builtin_fmaf(-2.0f, __builtin_amdgcn_rcpf(1.0f + e), 1.0f);
}
__device__ __forceinline__ float fast_silu(float x) {
  float e = __builtin_amdgcn_exp2f(x * -1.4426950408889634f); // -log2(e)
  return x * __builtin_amdgcn_rcpf(1.0f + e);
}
__device__ __forceinline__ uint32_t pk2(float a, float b) {
  union { f16x2 h; uint32_t u; } c;
  c.h = __builtin_amdgcn_cvt_pkrtz(a, b);
  return c.u;
}
__device__ __forceinline__ f16x8 pack8(f32x4 a, f32x4 b) {
  union { f16x8 v; f16x2 h[4]; } u;
  u.h[0] = __builtin_amdgcn_cvt_pkrtz(a.x, a.y);
  u.h[1] = __builtin_amdgcn_cvt_pkrtz(a.z, a.w);
  u.h[2] = __builtin_amdgcn_cvt_pkrtz(b.x, b.y);
  u.h[3] = __builtin_amdgcn_cvt_pkrtz(b.z, b.w);
  return u.v;
}

// ws layout (bytes):
//   [0, 1M)            wsz   : z_aug f32 [4096][64]
//   [1M, 1M+224K)      wpak  : packed A-frags (224 frags x 1 KB)
//   [1M+256K, +64K)    Ubuf  : U = W3@W1, f32 [128][128]  (row k=h2-unit, col m=g-unit)
//   [1M+320K, +2K)     cbuf  : [0..127]=c=b3@W1; [128..255]=Vt[c=0]; [256..383]=Vt[1];
//                              [384..385]=cv=b3@decW
#define WS_WPAK   (1u<<20)
#define WS_UBUF   ((1u<<20) + (256u<<10))
#define WS_CBUF   ((1u<<20) + (320u<<10))

// ---------------------------------------------------------------------------
// Kernel 0: compose U = W3@W1, c = b3@W1, Vt = (W3@decW)^T, cv = b3@decW.
// Also zeroes the loss slot.  Grid 65 x 256.
// R4 FIX: the g==64 tail block now strides tid over ALL 386 elements; R3 only
// covered e<256, leaving Vt[1] and cv as 0xAA poison -> stop_logits froze.
// ---------------------------------------------------------------------------
__global__ void compose_kernel(const float* __restrict__ oW1, const float* __restrict__ oW3,
                               const float* __restrict__ ob3, const float* __restrict__ dW,
                               float* __restrict__ Ubuf, float* __restrict__ cbuf,
                               float* __restrict__ dout) {
  int g = blockIdx.x;
  int tid = threadIdx.x;
  if (g < 64) {
    int e = g * 256 + tid;           // U element
    int i = e >> 7, j = e & 127;     // U[i][j] = sum_k W3[i][k] * W1[k][j]
    float s = 0.f;
    #pragma unroll 4
    for (int k = 0; k < 64; k++) s = __builtin_fmaf(oW3[i * 64 + k], oW1[k * 128 + j], s);
    Ubuf[i * 128 + j] = s;
  } else {
    for (int e = tid; e < 386; e += 256) {
      if (e < 128) {                 // c[j] = sum_k b3[k] * W1[k][j]
        float s = 0.f;
        for (int k = 0; k < 64; k++) s = __builtin_fmaf(ob3[k], oW1[k * 128 + e], s);
        cbuf[e] = s;
      } else if (e < 384) {          // Vt[c][u] = sum_k W3[u][k] * decW[k][c]
        int idx = e - 128, cc = idx >> 7, u = idx & 127;
        float s = 0.f;
        for (int k = 0; k < 64; k++) s = __builtin_fmaf(oW3[u * 64 + k], dW[k * 2 + cc], s);
        cbuf[128 + cc * 128 + u] = s;
      } else {                       // cv[c] = sum_k b3[k] * decW[k][c]
        int cc = e - 384;
        float s = 0.f;
        for (int k = 0; k < 64; k++) s = __builtin_fmaf(ob3[k], dW[k * 2 + cc], s);
        cbuf[384 + cc] = s;
      }
    }
    if (tid == 255) dout[LOSSOFF] = 0.0f;
  }
}

// ---------------------------------------------------------------------------
// Kernel 1: repack weight matrices ([K][M] row-major f32) into MFMA A-operand
// f16 fragments: A[m=lane&15][k=kt*32+(lane>>4)*8+j].  1 KB per frag.
//   [0,16)  ode_W1 (M=128,Kt=2)   [16,48) ode_W2 (M=128,Kt=4)
//   [48,64) ode_W3 (unused now)   [64,80) den_W1 (M=128,Kt=2)
//   [80,96) den_W2 (M=64, Kt=4)   [96,192) proj_W (M=64,Kt=24)
//   [192,224) U    (M=128,Kt=4)
// ---------------------------------------------------------------------------
__global__ void pack_kernel(const float* __restrict__ oW1, const float* __restrict__ oW2,
                            const float* __restrict__ oW3, const float* __restrict__ dW1,
                            const float* __restrict__ dW2, const float* __restrict__ pW,
                            const float* __restrict__ Ubuf, char* __restrict__ wdst) {
  int g = blockIdx.x * 256 + threadIdx.x;
  int fid = g >> 6, lane = g & 63;
  if (fid >= 224) return;
  const float* src; int Kt, M, base;
  if      (fid < 16)  { src = oW1;  Kt = 2;  M = 128; base = 0;   }
  else if (fid < 48)  { src = oW2;  Kt = 4;  M = 128; base = 16;  }
  else if (fid < 64)  { src = oW3;  Kt = 4;  M = 64;  base = 48;  }
  else if (fid < 80)  { src = dW1;  Kt = 2;  M = 128; base = 64;  }
  else if (fid < 96)  { src = dW2;  Kt = 4;  M = 64;  base = 80;  }
  else if (fid < 192) { src = pW;   Kt = 24; M = 64;  base = 96;  }
  else                { src = Ubuf; Kt = 4;  M = 128; base = 192; }
  int local = fid - base;
  int mt = local / Kt, kt = local % Kt;
  int m  = mt * 16 + (lane & 15);
  int k0 = kt * 32 + (lane >> 4) * 8;
  f16x8 out;
  #pragma unroll
  for (int j = 0; j < 8; j++) out[j] = (__fp16)src[(size_t)(k0 + j) * M + m];
  *(f16x8*)(wdst + (size_t)(fid * 64 + lane) * 16) = out;
}

// ---------------------------------------------------------------------------
// Kernel 2: prologue (unchanged — verified in R2).  256 WGs x 512 threads,
// 16 rows each: proj -> LN -> +sigma*eps -> denoiser -> z_aug -> wsz; loss.
// ---------------------------------------------------------------------------
__global__ __launch_bounds__(512, 2) void prologue_kernel(
    const float* __restrict__ bert, const float* __restrict__ eps,
    const float* __restrict__ projb, const float* __restrict__ lng,
    const float* __restrict__ lnb,  const float* __restrict__ lns,
    const float* __restrict__ db1,  const float* __restrict__ db2,
    const char* __restrict__ wpack, float* __restrict__ wsz,
    float* __restrict__ dout) {
  __shared__ __attribute__((aligned(16))) char sZ[16 * 128];
  __shared__ __attribute__((aligned(16))) char sH[16 * 256];
  __shared__ f32x4  sScr[4 * 64];
  __shared__ float2 sMV[64];
  __shared__ float  sLsum[4];

  const int tid  = threadIdx.x;
  const int wave = tid >> 6, lane = tid & 63;
  const int q = lane >> 4, b = lane & 15;
  const int bg = blockIdx.x * 16 + b;
  const int b7 = b & 7;
  const f16x8* wp = (const f16x8*)wpack;
  const int u0 = wave * 16 + q * 4;

  const int zr0 = b * 128 + ((q    ) ^ b7) * 16;
  const int zr1 = b * 128 + ((q + 4) ^ b7) * 16;
  int hr[4];
  #pragma unroll
  for (int s = 0; s < 4; s++) hr[s] = b * 256 + ((4 * s + q) ^ b7) * 16;
  const int hw = b * 256 + (((2 * wave + (q >> 1)) ^ b7) * 16) + (q & 1) * 8;
  const int zw = b * 128 + (((2 * (wave & 3) + (q >> 1)) ^ b7) * 16) + (q & 1) * 8;

  const int mt = wave & 3, kh = wave >> 2;
  f32x4 hA = {0,0,0,0}, hB = {0,0,0,0};
  #pragma unroll 4
  for (int i = 0; i < 12; i++) {
    int kt = kh * 12 + i;
    f16x8 af = wp[(size_t)(96 + mt * 24 + kt) * 64 + lane];
    const float* bp = bert + (size_t)bg * 768 + kt * 32 + q * 8;
    f32x4 f0 = *(const f32x4*)bp;
    f32x4 f1 = *(const f32x4*)(bp + 4);
    f16x8 bf = pack8(f0, f1);
    if (i & 1) hB = MFMA(af, bf, hB); else hA = MFMA(af, bf, hA);
  }
  f32x4 hacc = hA + hB;
  if (wave >= 4) sScr[(wave - 4) * 64 + lane] = hacc;
  __syncthreads();

  f32x4 h = {0,0,0,0}, zc = {0,0,0,0};
  if (wave < 4) {
    h = hacc + sScr[wave * 64 + lane];
    h.x += projb[u0 + 0]; h.y += projb[u0 + 1];
    h.z += projb[u0 + 2]; h.w += projb[u0 + 3];
    float s1 = h.x + h.y + h.z + h.w;
    float s2 = h.x*h.x + h.y*h.y + h.z*h.z + h.w*h.w;
    s1 += __shfl_xor(s1, 16); s1 += __shfl_xor(s1, 32);
    s2 += __shfl_xor(s2, 16); s2 += __shfl_xor(s2, 32);
    if (q == 0) sMV[wave * 16 + b] = make_float2(s1, s2);
  }
  __syncthreads();
  if (wave < 4) {
    float t1 = 0.f, t2 = 0.f;
    #pragma unroll
    for (int w2 = 0; w2 < 4; w2++) { float2 m = sMV[w2 * 16 + b]; t1 += m.x; t2 += m.y; }
    float mu  = t1 * (1.0f / 64.0f);
    float var = t2 * (1.0f / 64.0f) - mu * mu;
    float rs  = rsqrtf(var + 1e-5f);
    float sigma = logf(1.0f + expf(lns[0]));
    f32x4 e = *(const f32x4*)(eps + (size_t)bg * 64 + u0);
    zc.x = __builtin_fmaf((h.x - mu) * rs, lng[u0+0], lnb[u0+0]);
    zc.y = __builtin_fmaf((h.y - mu) * rs, lng[u0+1], lnb[u0+1]);
    zc.z = __builtin_fmaf((h.z - mu) * rs, lng[u0+2], lnb[u0+2]);
    zc.w = __builtin_fmaf((h.w - mu) * rs, lng[u0+3], lnb[u0+3]);
    f32x4 zn = zc + sigma * e;
    *(uint2*)(sZ + zw) = make_uint2(pk2(zn.x, zn.y), pk2(zn.z, zn.w));
  }
  __syncthreads();
  {
    f16x8 w0 = wp[(size_t)(64 + wave * 2 + 0) * 64 + lane];
    f16x8 w1 = wp[(size_t)(64 + wave * 2 + 1) * 64 + lane];
    f16x8 bz0 = *(const f16x8*)(sZ + zr0);
    f16x8 bz1 = *(const f16x8*)(sZ + zr1);
    f32x4 bias = { db1[u0+0], db1[u0+1], db1[u0+2], db1[u0+3] };
    f32x4 acc = MFMA(w0, bz0, bias);
    acc = MFMA(w1, bz1, acc);
    *(uint2*)(sH + hw) = make_uint2(pk2(fast_silu(acc.x), fast_silu(acc.y)),
                                    pk2(fast_silu(acc.z), fast_silu(acc.w)));
  }
  __syncthreads();
  if (wave < 4) {
    f16x8 w0 = wp[(size_t)(80 + wave * 4 + 0) * 64 + lane];
    f16x8 w1 = wp[(size_t)(80 + wave * 4 + 1) * 64 + lane];
    f16x8 w2 = wp[(size_t)(80 + wave * 4 + 2) * 64 + lane];
    f16x8 w3 = wp[(size_t)(80 + wave * 4 + 3) * 64 + lane];
    f16x8 g0 = *(const f16x8*)(sH + hr[0]);
    f16x8 g1 = *(const f16x8*)(sH + hr[1]);
    f16x8 g2 = *(const f16x8*)(sH + hr[2]);
    f16x8 g3 = *(const f16x8*)(sH + hr[3]);
    f32x4 bias = { db2[u0+0], db2[u0+1], db2[u0+2], db2[u0+3] };
    const f32x4 z4 = {0,0,0,0};
    f32x4 aA = MFMA(w0, g0, bias); aA = MFMA(w1, g1, aA);
    f32x4 aB = MFMA(w2, g2, z4);   aB = MFMA(w3, g3, aB);
    f32x4 za = aA + aB;
    *(f32x4*)(wsz + (size_t)bg * 64 + u0) = za;
    f32x4 d = za - zc;
    float sl = d.x*d.x + d.y*d.y + d.z*d.z + d.w*d.w;
    const int offs[6] = {1, 2, 4, 8, 16, 32};
    #pragma unroll
    for (int i = 0; i < 6; i++) sl += __shfl_xor(sl, offs[i]);
    if (lane == 0) sLsum[wave] = sl;
  }
  __syncthreads();
  if (tid == 0)
    atomicAdd(dout + LOSSOFF,
              (sLsum[0] + sLsum[1] + sLsum[2] + sLsum[3]) * (1.0f / 262144.0f));
}

// ---------------------------------------------------------------------------
// Kernel 3: ODE scan, composite form.  512 WGs x 256 threads (4 waves),
// 8 batch rows each (N=16 MFMA tiles, cols 8-15 duplicate rows 0-7),
// 2 blocks/CU.  State: G = z@W1 + b1 (f32, C-layout, 2 M-tiles/wave);
// loop: phase A: h2 = tanh(h1@W2 + b2) -> LDS; dec partials (h2@Vt).
//       phase B: G += dt*(h2@U + c); h1 = tanh(G) -> LDS; wave3: p += dt*(sum+cv),
//       store out[t+1].  2 barriers/step.  z never materialized in-loop.
// ---------------------------------------------------------------------------
__global__ __launch_bounds__(256, 2) void ode_kernel(
    const float* __restrict__ wsz, const char* __restrict__ wpack,
    const float* __restrict__ ob1, const float* __restrict__ cbuf,
    const float* __restrict__ ob2, const float* __restrict__ decW,
    const float* __restrict__ decb, float* __restrict__ dout) {
  __shared__ __attribute__((aligned(16))) char sH1[16 * 256];  // h1 f16 [b][128]
  __shared__ __attribute__((aligned(16))) char sH2[16 * 256];  // h2 f16 [b][128]
  __shared__ float2 sPart[64];                                 // dec partials [w][b]
  __shared__ float2 sP0[16];                                   // p0 partials [b]

  const int tid  = threadIdx.x;
  const int wave = tid >> 6, lane = tid & 63;
  const int q = lane >> 4, b = lane & 15;
  const f16x8* wp = (const f16x8*)wpack;
  const float dtc = 1.0f / 512.0f;
  const f32x4 zero4 = {0,0,0,0};

  // LDS addresses: rows [b][128 units] = 16 chunks of 16B, chunk XOR-swizzled by b.
  int rdA[4];                                   // B-frag reads, kt=0..3
  #pragma unroll
  for (int kt = 0; kt < 4; kt++) rdA[kt] = b * 256 + (((kt * 4 + q) ^ b) * 16);
  int wrT[2];                                   // product writes, tile t2=0,1
  #pragma unroll
  for (int t2 = 0; t2 < 2; t2++)
    wrT[t2] = b * 256 + (((4 * wave + 2 * t2 + (q >> 1)) ^ b) * 16) + (q & 1) * 8;

  // Persistent weights: W2 tiles {2w,2w+1} and U tiles {2w,2w+1}, 4 K-frags each
  f16x8 w2f[8], uf[8];
  #pragma unroll
  for (int t2 = 0; t2 < 2; t2++)
    #pragma unroll
    for (int kt = 0; kt < 4; kt++) {
      w2f[t2 * 4 + kt] = wp[(size_t)(16  + (2 * wave + t2) * 4 + kt) * 64 + lane];
      uf [t2 * 4 + kt] = wp[(size_t)(192 + (2 * wave + t2) * 4 + kt) * 64 + lane];
    }
  // Per-tile constant vectors
  f32x4 b2f[2], cf[2], vb0[2], vb1[2];
  #pragma unroll
  for (int t2 = 0; t2 < 2; t2++) {
    int u0t = wave * 32 + t2 * 16 + q * 4;
    b2f[t2] = *(const f32x4*)(ob2 + u0t);
    cf [t2] = *(const f32x4*)(cbuf + u0t);          // c = b3@W1
    vb0[t2] = *(const f32x4*)(cbuf + 128 + u0t);    // Vt[0]
    vb1[t2] = *(const f32x4*)(cbuf + 256 + u0t);    // Vt[1]
  }

  // ---- init: G = z_aug@W1 + b1 ; h1_0 = tanh(G) ; p0 partials (wave 0) ----
  const int bgz = blockIdx.x * 8 + (b & 7);         // cols 8-15 duplicate 0-7
  const float* zrow = wsz + (size_t)bgz * 64;
  f32x4 z0a = *(const f32x4*)(zrow + q * 8);
  f32x4 z0b = *(const f32x4*)(zrow + q * 8 + 4);
  f32x4 z1a = *(const f32x4*)(zrow + 32 + q * 8);
  f32x4 z1b = *(const f32x4*)(zrow + 32 + q * 8 + 4);
  f16x8 zf0 = pack8(z0a, z0b);
  f16x8 zf1 = pack8(z1a, z1b);

  f32x4 G[2];
  #pragma unroll
  for (int t2 = 0; t2 < 2; t2++) {
    int mt = 2 * wave + t2;
    f32x4 b1v = *(const f32x4*)(ob1 + mt * 16 + q * 4);
    f32x4 d = MFMA(wp[(size_t)(mt * 2 + 0) * 64 + lane], zf0, b1v);
    d = MFMA(wp[(size_t)(mt * 2 + 1) * 64 + lane], zf1, d);
    G[t2] = d;
    *(uint2*)(sH1 + wrT[t2]) = make_uint2(pk2(fast_tanh(d.x), fast_tanh(d.y)),
                                          pk2(fast_tanh(d.z), fast_tanh(d.w)));
  }
  if (wave == 0) {   // p0 partials: z_aug . decW (uses exact f32 z values)
    float pp = 0.f, ss = 0.f;
    const float za[8] = {z0a.x,z0a.y,z0a.z,z0a.w,z0b.x,z0b.y,z0b.z,z0b.w};
    const float zb[8] = {z1a.x,z1a.y,z1a.z,z1a.w,z1b.x,z1b.y,z1b.z,z1b.w};
    #pragma unroll
    for (int j = 0; j < 8; j++) {
      int k1 = q * 8 + j, k2 = 32 + q * 8 + j;
      pp = __builtin_fmaf(za[j], decW[k1*2],   pp);
      pp = __builtin_fmaf(zb[j], decW[k2*2],   pp);
      ss = __builtin_fmaf(za[j], decW[k1*2+1], ss);
      ss = __builtin_fmaf(zb[j], decW[k2*2+1], ss);
    }
    pp += __shfl_xor(pp, 16); pp += __shfl_xor(pp, 32);
    ss += __shfl_xor(ss, 16); ss += __shfl_xor(ss, 32);
    if (q == 0) sP0[b] = make_float2(pp, ss);
  }
  wg_barrier();

  // decode owner: wave 3, lanes 0-31: c = lane>>4, row = lane&15 (valid < 8)
  float p = 0.f, cvc = 0.f, decbc = 0.f;
  float* outp = dout;
  const int b2 = lane & 15, cc = (lane >> 4) & 1;
  const bool decl = (wave == 3) && (lane < 32);
  if (decl) {
    cvc   = cbuf[384 + cc];
    decbc = decb[cc];
    const float* pf = (const float*)sP0;
    p = pf[b2 * 2 + cc] + decbc;
    outp = dout + (size_t)cc * TOTE + (size_t)(blockIdx.x * 8 + (b2 & 7)) * OT;
    if (b2 < 8) outp[0] = p;
  }

  #pragma unroll 1
  for (int t = 0; t < NT; ++t) {
    // ---- phase A: h2 = tanh(h1@W2 + b2); dec partials ----
    f16x8 h1f0 = *(const f16x8*)(sH1 + rdA[0]);
    f16x8 h1f1 = *(const f16x8*)(sH1 + rdA[1]);
    f16x8 h1f2 = *(const f16x8*)(sH1 + rdA[2]);
    f16x8 h1f3 = *(const f16x8*)(sH1 + rdA[3]);
    f32x4 h2v[2];
    #pragma unroll
    for (int t2 = 0; t2 < 2; t2++) {
      f32x4 a  = MFMA(w2f[t2*4+0], h1f0, b2f[t2]);
      a  = MFMA(w2f[t2*4+1], h1f1, a);
      f32x4 a2 = MFMA(w2f[t2*4+2], h1f2, zero4);
      a2 = MFMA(w2f[t2*4+3], h1f3, a2);
      f32x4 hv = a + a2;
      hv.x = fast_tanh(hv.x); hv.y = fast_tanh(hv.y);
      hv.z = fast_tanh(hv.z); hv.w = fast_tanh(hv.w);
      h2v[t2] = hv;
      *(uint2*)(sH2 + wrT[t2]) = make_uint2(pk2(hv.x, hv.y), pk2(hv.z, hv.w));
    }
    {
      float pp = 0.f, ss = 0.f;
      #pragma unroll
      for (int t2 = 0; t2 < 2; t2++) {
        pp = __builtin_fmaf(h2v[t2].x, vb0[t2].x, pp);
        pp = __builtin_fmaf(h2v[t2].y, vb0[t2].y, pp);
        pp = __builtin_fmaf(h2v[t2].z, vb0[t2].z, pp);
        pp = __builtin_fmaf(h2v[t2].w, vb0[t2].w, pp);
        ss = __builtin_fmaf(h2v[t2].x, vb1[t2].x, ss);
        ss = __builtin_fmaf(h2v[t2].y, vb1[t2].y, ss);
        ss = __builtin_fmaf(h2v[t2].z, vb1[t2].z, ss);
        ss = __builtin_fmaf(h2v[t2].w, vb1[t2].w, ss);
      }
      pp += __shfl_xor(pp, 16); pp += __shfl_xor(pp, 32);
      ss += __shfl_xor(ss, 16); ss += __shfl_xor(ss, 32);
      if (q == 0) sPart[wave * 16 + b] = make_float2(pp, ss);
    }
    wg_barrier();

    // ---- phase B: G += dt*(h2@U + c); h1' = tanh(G); decode finalize ----
    f16x8 h2f0 = *(const f16x8*)(sH2 + rdA[0]);
    f16x8 h2f1 = *(const f16x8*)(sH2 + rdA[1]);
    f16x8 h2f2 = *(const f16x8*)(sH2 + rdA[2]);
    f16x8 h2f3 = *(const f16x8*)(sH2 + rdA[3]);
    #pragma unroll
    for (int t2 = 0; t2 < 2; t2++) {
      f32x4 d  = MFMA(uf[t2*4+0], h2f0, cf[t2]);
      d  = MFMA(uf[t2*4+1], h2f1, d);
      f32x4 d2 = MFMA(uf[t2*4+2], h2f2, zero4);
      d2 = MFMA(uf[t2*4+3], h2f3, d2);
      f32x4 Gn = G[t2];
      Gn.x = __builtin_fmaf(dtc, d.x + d2.x, Gn.x);
      Gn.y = __builtin_fmaf(dtc, d.y + d2.y, Gn.y);
      Gn.z = __builtin_fmaf(dtc, d.z + d2.z, Gn.z);
      Gn.w = __builtin_fmaf(dtc, d.w + d2.w, Gn.w);
      G[t2] = Gn;
      *(uint2*)(sH1 + wrT[t2]) = make_uint2(pk2(fast_tanh(Gn.x), fast_tanh(Gn.y)),
                                            pk2(fast_tanh(Gn.z), fast_tanh(Gn.w)));
    }
    if (decl) {
      const float* pf = (const float*)sPart;
      float s = pf[(0*16+b2)*2+cc] + pf[(1*16+b2)*2+cc]
              + pf[(2*16+b2)*2+cc] + pf[(3*16+b2)*2+cc];
      p = __builtin_fmaf(dtc, s + cvc, p);
      if (b2 < 8) outp[t + 1] = p;
    }
    wg_barrier();
  }
}

// ---------------------------------------------------------------------------
extern "C" void kernel_launch(void* const* d_in, const int* in_sizes, int n_in,
                              void* d_out, int out_size, void* d_ws, size_t ws_size,
                              hipStream_t stream) {
  const float* bert  = (const float*)d_in[0];
  const float* eps   = (const float*)d_in[3];
  const float* projW = (const float*)d_in[4];
  const float* projb = (const float*)d_in[5];
  const float* lng   = (const float*)d_in[6];
  const float* lnb   = (const float*)d_in[7];
  const float* lns   = (const float*)d_in[8];
  const float* denW1 = (const float*)d_in[9];
  const float* denb1 = (const float*)d_in[10];
  const float* denW2 = (const float*)d_in[11];
  const float* denb2 = (const float*)d_in[12];
  const float* odeW1 = (const float*)d_in[13];
  const float* odeb1 = (const float*)d_in[14];
  const float* odeW2 = (const float*)d_in[15];
  const float* odeb2 = (const float*)d_in[16];
  const float* odeW3 = (const float*)d_in[17];
  const float* odeb3 = (const float*)d_in[18];
  const float* decW  = (const float*)d_in[19];
  const float* decb  = (const float*)d_in[20];
  float* dout = (float*)d_out;

  float* wsz  = (float*)d_ws;
  char*  wpak = (char*)d_ws + WS_WPAK;
  float* Ubuf = (float*)((char*)d_ws + WS_UBUF);
  float* cbuf = (float*)((char*)d_ws + WS_CBUF);

  compose_kernel<<<65, 256, 0, stream>>>(odeW1, odeW3, odeb3, decW, Ubuf, cbuf, dout);
  pack_kernel<<<56, 256, 0, stream>>>(odeW1, odeW2, odeW3, denW1, denW2, projW, Ubuf, wpak);
  prologue_kernel<<<256, 512, 0, stream>>>(bert, eps, projb, lng, lnb, lns,
                                           denb1, denb2, wpak, wsz, dout);
  ode_kernel<<<512, 256, 0, stream>>>(wsz, wpak, odeb1, cbuf, odeb2, decW, decb, dout);
}

// Round 5
// 428.517 us; speedup vs baseline: 1.4374x; 1.4374x over previous
//
#include <hip/hip_runtime.h>
#include <stdint.h>

// Problem constants
#define NB 4096
#define NT 512
#define OT 513
#define TOTE (NB*OT)          // 2101248 elements per output matrix
#define LOSSOFF (2*TOTE)      // diff_loss slot

typedef float  f32x4 __attribute__((ext_vector_type(4)));
typedef __fp16 f16x8 __attribute__((ext_vector_type(8)));
typedef __fp16 f16x2 __attribute__((ext_vector_type(2)));

#define MFMA(A,B,C) __builtin_amdgcn_mfma_f32_16x16x32_f16((A),(B),(C),0,0,0)

// Barrier that drains LDS only (no vmcnt(0) drain -> global stores stay in flight)
__device__ __forceinline__ void wg_barrier() {
  asm volatile("s_waitcnt lgkmcnt(0)\n\ts_barrier" ::: "memory");
}

__device__ __forceinline__ float fast_tanh(float x) {
  float e = __builtin_amdgcn_exp2f(x * 2.8853900817779268f); // 2*log2(e)
  return __builtin_fmaf(-2.0f, __builtin_amdgcn_rcpf(1.0f + e), 1.0f);
}
__device__ __forceinline__ float fast_silu(float x) {
  float e = __builtin_amdgcn_exp2f(x * -1.4426950408889634f); // -log2(e)
  return x * __builtin_amdgcn_rcpf(1.0f + e);
}
__device__ __forceinline__ uint32_t pk2(float a, float b) {
  union { f16x2 h; uint32_t u; } c;
  c.h = __builtin_amdgcn_cvt_pkrtz(a, b);
  return c.u;
}
__device__ __forceinline__ f16x8 pack8(f32x4 a, f32x4 b) {
  union { f16x8 v; f16x2 h[4]; } u;
  u.h[0] = __builtin_amdgcn_cvt_pkrtz(a.x, a.y);
  u.h[1] = __builtin_amdgcn_cvt_pkrtz(a.z, a.w);
  u.h[2] = __builtin_amdgcn_cvt_pkrtz(b.x, b.y);
  u.h[3] = __builtin_amdgcn_cvt_pkrtz(b.z, b.w);
  return u.v;
}

// ws layout (bytes):
//   [0, 1M)          wsz  : z_aug f32 [4096][64]
//   [1M, +228K)      wpak : packed A-frags (228 frags x 1 KB)
//   [1M+256K, +72K)  Ubuf : U_ext = W3@[W1|decW|0], f32 [128][144]
//   [1M+384K, 576B)  cbuf : c_ext = [b3@W1 (128) | b3@decW (2) | 0 (14)]
#define WS_WPAK (1u<<20)
#define WS_UBUF ((1u<<20) + (256u<<10))
#define WS_CBUF ((1u<<20) + (384u<<10))

// ---------------------------------------------------------------------------
// Kernel 0: compose U_ext (128x144) and c_ext (144); zero the loss slot.
// Grid 73 x 256.  Cols: [0,128)=W3@W1, 128/129=W3@decW, [130,144)=0.
// ---------------------------------------------------------------------------
__global__ void compose_kernel(const float* __restrict__ oW1, const float* __restrict__ oW3,
                               const float* __restrict__ ob3, const float* __restrict__ dW,
                               float* __restrict__ Ubuf, float* __restrict__ cbuf,
                               float* __restrict__ dout) {
  int g = blockIdx.x, tid = threadIdx.x;
  if (g < 72) {
    int e = g * 256 + tid;          // 0..18431
    int i = e / 144, j = e - i * 144;
    float s = 0.f;
    if (j < 128) {
      #pragma unroll 4
      for (int k = 0; k < 64; k++) s = __builtin_fmaf(oW3[i * 64 + k], oW1[k * 128 + j], s);
    } else if (j < 130) {
      int cc = j - 128;
      for (int k = 0; k < 64; k++) s = __builtin_fmaf(oW3[i * 64 + k], dW[k * 2 + cc], s);
    }
    Ubuf[i * 144 + j] = s;
  } else {
    if (tid < 144) {
      float s = 0.f;
      if (tid < 128) {
        for (int k = 0; k < 64; k++) s = __builtin_fmaf(ob3[k], oW1[k * 128 + tid], s);
      } else if (tid < 130) {
        int cc = tid - 128;
        for (int k = 0; k < 64; k++) s = __builtin_fmaf(ob3[k], dW[k * 2 + cc], s);
      }
      cbuf[tid] = s;
    }
    if (tid == 255) dout[LOSSOFF] = 0.0f;
  }
}

// ---------------------------------------------------------------------------
// Kernel 1: repack weights ([K][M] row-major f32) into MFMA A-operand f16
// fragments: A[m=lane&15][k=kt*32+(lane>>4)*8+j].  1 KB per frag.
//   [0,16)  ode_W1 (M=128,Kt=2)   [16,48)  ode_W2 (M=128,Kt=4)
//   [48,50) decW^T (M=16[2 real],Kt=2)     [50,64)  unused
//   [64,80) den_W1 (M=128,Kt=2)   [80,96)  den_W2 (M=64,Kt=4)
//   [96,192) proj_W (M=64,Kt=24)  [192,228) U_ext (M=144,Kt=4)
// ---------------------------------------------------------------------------
__global__ void pack_kernel(const float* __restrict__ oW1, const float* __restrict__ oW2,
                            const float* __restrict__ dW,  const float* __restrict__ dW1,
                            const float* __restrict__ dW2, const float* __restrict__ pW,
                            const float* __restrict__ Ubuf, char* __restrict__ wdst) {
  int g = blockIdx.x * 256 + threadIdx.x;
  int fid = g >> 6, lane = g & 63;
  if (fid >= 228 || (fid >= 50 && fid < 64)) return;
  int m4 = lane & 15;
  if (fid >= 48 && fid < 50) {       // decW^T: A[m][k] = decW[k][m], m<2
    int kt = fid - 48;
    int k0 = kt * 32 + (lane >> 4) * 8;
    f16x8 out;
    #pragma unroll
    for (int j = 0; j < 8; j++) out[j] = (m4 < 2) ? (__fp16)dW[(k0 + j) * 2 + m4] : (__fp16)0.f;
    *(f16x8*)(wdst + (size_t)(fid * 64 + lane) * 16) = out;
    return;
  }
  const float* src; int Kt, M, base;
  if      (fid < 16)  { src = oW1;  Kt = 2;  M = 128; base = 0;   }
  else if (fid < 48)  { src = oW2;  Kt = 4;  M = 128; base = 16;  }
  else if (fid < 80)  { src = dW1;  Kt = 2;  M = 128; base = 64;  }
  else if (fid < 96)  { src = dW2;  Kt = 4;  M = 64;  base = 80;  }
  else if (fid < 192) { src = pW;   Kt = 24; M = 64;  base = 96;  }
  else                { src = Ubuf; Kt = 4;  M = 144; base = 192; }
  int local = fid - base;
  int mt = local / Kt, kt = local % Kt;
  int m  = mt * 16 + m4;
  int k0 = kt * 32 + (lane >> 4) * 8;
  f16x8 out;
  #pragma unroll
  for (int j = 0; j < 8; j++) out[j] = (__fp16)src[(size_t)(k0 + j) * M + m];
  *(f16x8*)(wdst + (size_t)(fid * 64 + lane) * 16) = out;
}

// ---------------------------------------------------------------------------
// Kernel 2: prologue (unchanged — verified R2/R4).  256 WGs x 512 threads,
// 16 rows each: proj -> LN -> +sigma*eps -> denoiser -> z_aug -> wsz; loss.
// ---------------------------------------------------------------------------
__global__ __launch_bounds__(512, 2) void prologue_kernel(
    const float* __restrict__ bert, const float* __restrict__ eps,
    const float* __restrict__ projb, const float* __restrict__ lng,
    const float* __restrict__ lnb,  const float* __restrict__ lns,
    const float* __restrict__ db1,  const float* __restrict__ db2,
    const char* __restrict__ wpack, float* __restrict__ wsz,
    float* __restrict__ dout) {
  __shared__ __attribute__((aligned(16))) char sZ[16 * 128];
  __shared__ __attribute__((aligned(16))) char sH[16 * 256];
  __shared__ f32x4  sScr[4 * 64];
  __shared__ float2 sMV[64];
  __shared__ float  sLsum[4];

  const int tid  = threadIdx.x;
  const int wave = tid >> 6, lane = tid & 63;
  const int q = lane >> 4, b = lane & 15;
  const int bg = blockIdx.x * 16 + b;
  const int b7 = b & 7;
  const f16x8* wp = (const f16x8*)wpack;
  const int u0 = wave * 16 + q * 4;

  const int zr0 = b * 128 + ((q    ) ^ b7) * 16;
  const int zr1 = b * 128 + ((q + 4) ^ b7) * 16;
  int hr[4];
  #pragma unroll
  for (int s = 0; s < 4; s++) hr[s] = b * 256 + ((4 * s + q) ^ b7) * 16;
  const int hw = b * 256 + (((2 * wave + (q >> 1)) ^ b7) * 16) + (q & 1) * 8;
  const int zw = b * 128 + (((2 * (wave & 3) + (q >> 1)) ^ b7) * 16) + (q & 1) * 8;

  const int mt = wave & 3, kh = wave >> 2;
  f32x4 hA = {0,0,0,0}, hB = {0,0,0,0};
  #pragma unroll 4
  for (int i = 0; i < 12; i++) {
    int kt = kh * 12 + i;
    f16x8 af = wp[(size_t)(96 + mt * 24 + kt) * 64 + lane];
    const float* bp = bert + (size_t)bg * 768 + kt * 32 + q * 8;
    f32x4 f0 = *(const f32x4*)bp;
    f32x4 f1 = *(const f32x4*)(bp + 4);
    f16x8 bf = pack8(f0, f1);
    if (i & 1) hB = MFMA(af, bf, hB); else hA = MFMA(af, bf, hA);
  }
  f32x4 hacc = hA + hB;
  if (wave >= 4) sScr[(wave - 4) * 64 + lane] = hacc;
  __syncthreads();

  f32x4 h = {0,0,0,0}, zc = {0,0,0,0};
  if (wave < 4) {
    h = hacc + sScr[wave * 64 + lane];
    h.x += projb[u0 + 0]; h.y += projb[u0 + 1];
    h.z += projb[u0 + 2]; h.w += projb[u0 + 3];
    float s1 = h.x + h.y + h.z + h.w;
    float s2 = h.x*h.x + h.y*h.y + h.z*h.z + h.w*h.w;
    s1 += __shfl_xor(s1, 16); s1 += __shfl_xor(s1, 32);
    s2 += __shfl_xor(s2, 16); s2 += __shfl_xor(s2, 32);
    if (q == 0) sMV[wave * 16 + b] = make_float2(s1, s2);
  }
  __syncthreads();
  if (wave < 4) {
    float t1 = 0.f, t2 = 0.f;
    #pragma unroll
    for (int w2 = 0; w2 < 4; w2++) { float2 m = sMV[w2 * 16 + b]; t1 += m.x; t2 += m.y; }
    float mu  = t1 * (1.0f / 64.0f);
    float var = t2 * (1.0f / 64.0f) - mu * mu;
    float rs  = rsqrtf(var + 1e-5f);
    float sigma = logf(1.0f + expf(lns[0]));
    f32x4 e = *(const f32x4*)(eps + (size_t)bg * 64 + u0);
    zc.x = __builtin_fmaf((h.x - mu) * rs, lng[u0+0], lnb[u0+0]);
    zc.y = __builtin_fmaf((h.y - mu) * rs, lng[u0+1], lnb[u0+1]);
    zc.z = __builtin_fmaf((h.z - mu) * rs, lng[u0+2], lnb[u0+2]);
    zc.w = __builtin_fmaf((h.w - mu) * rs, lng[u0+3], lnb[u0+3]);
    f32x4 zn = zc + sigma * e;
    *(uint2*)(sZ + zw) = make_uint2(pk2(zn.x, zn.y), pk2(zn.z, zn.w));
  }
  __syncthreads();
  {
    f16x8 w0 = wp[(size_t)(64 + wave * 2 + 0) * 64 + lane];
    f16x8 w1 = wp[(size_t)(64 + wave * 2 + 1) * 64 + lane];
    f16x8 bz0 = *(const f16x8*)(sZ + zr0);
    f16x8 bz1 = *(const f16x8*)(sZ + zr1);
    f32x4 bias = { db1[u0+0], db1[u0+1], db1[u0+2], db1[u0+3] };
    f32x4 acc = MFMA(w0, bz0, bias);
    acc = MFMA(w1, bz1, acc);
    *(uint2*)(sH + hw) = make_uint2(pk2(fast_silu(acc.x), fast_silu(acc.y)),
                                    pk2(fast_silu(acc.z), fast_silu(acc.w)));
  }
  __syncthreads();
  if (wave < 4) {
    f16x8 w0 = wp[(size_t)(80 + wave * 4 + 0) * 64 + lane];
    f16x8 w1 = wp[(size_t)(80 + wave * 4 + 1) * 64 + lane];
    f16x8 w2 = wp[(size_t)(80 + wave * 4 + 2) * 64 + lane];
    f16x8 w3 = wp[(size_t)(80 + wave * 4 + 3) * 64 + lane];
    f16x8 g0 = *(const f16x8*)(sH + hr[0]);
    f16x8 g1 = *(const f16x8*)(sH + hr[1]);
    f16x8 g2 = *(const f16x8*)(sH + hr[2]);
    f16x8 g3 = *(const f16x8*)(sH + hr[3]);
    f32x4 bias = { db2[u0+0], db2[u0+1], db2[u0+2], db2[u0+3] };
    const f32x4 z4 = {0,0,0,0};
    f32x4 aA = MFMA(w0, g0, bias); aA = MFMA(w1, g1, aA);
    f32x4 aB = MFMA(w2, g2, z4);   aB = MFMA(w3, g3, aB);
    f32x4 za = aA + aB;
    *(f32x4*)(wsz + (size_t)bg * 64 + u0) = za;
    f32x4 d = za - zc;
    float sl = d.x*d.x + d.y*d.y + d.z*d.z + d.w*d.w;
    const int offs[6] = {1, 2, 4, 8, 16, 32};
    #pragma unroll
    for (int i = 0; i < 6; i++) sl += __shfl_xor(sl, offs[i]);
    if (lane == 0) sLsum[wave] = sl;
  }
  __syncthreads();
  if (tid == 0)
    atomicAdd(dout + LOSSOFF,
              (sLsum[0] + sLsum[1] + sLsum[2] + sLsum[3]) * (1.0f / 262144.0f));
}

// ---------------------------------------------------------------------------
// Kernel 3: ODE scan, composite + fused decode.  256 WGs x 512 threads
// (8 waves), 16 REAL rows/WG (full N=16 tiles, no duplication).
// State: G_ext = z@[W1|decW] + [b1|decb] (f32 C-layout).  Wave w owns M-tile w;
// wave 7 additionally owns tile 8 (decoder: units 128=pred, 129=stop).
// Per step: A) h2 = tanh(h1@W2+b2) -> sH2;  B) G += dt*(h2@U_ext + c_ext),
// h1 = tanh(G[0:128]) -> sH1, wave7 q==0 lanes store p(t+1) straight from C.
// 2 barriers/step, XOR-swizzled conflict-free LDS, 68 MFMA / 16 rows / step.
// ---------------------------------------------------------------------------
__global__ __launch_bounds__(512, 1) void ode_kernel(
    const float* __restrict__ wsz, const char* __restrict__ wpack,
    const float* __restrict__ ob1, const float* __restrict__ cbuf,
    const float* __restrict__ ob2, const float* __restrict__ decb,
    float* __restrict__ dout) {
  __shared__ __attribute__((aligned(16))) char sH1[4096];  // h1 f16 [b][128]
  __shared__ __attribute__((aligned(16))) char sH2[4096];  // h2 f16 [b][128]

  const int tid  = threadIdx.x;
  const int wave = tid >> 6, lane = tid & 63;
  const int q = lane >> 4, b = lane & 15;
  const f16x8* wp = (const f16x8*)wpack;
  const float dtc = 1.0f / 512.0f;
  const f32x4 zero4 = {0,0,0,0};

  // LDS addrs: row b = 16 chunks of 16B, chunk c at (c^b): banks provably even.
  int rd[4];
  #pragma unroll
  for (int kt = 0; kt < 4; kt++) rd[kt] = b * 256 + (((kt * 4 + q) ^ b) * 16);
  const int wr = b * 256 + (((wave * 2 + (q >> 1)) ^ b) * 16) + (q & 1) * 8;

  // Persistent weight fragments
  f16x8 w2f[4], uf[4], uf8[4];
  #pragma unroll
  for (int kt = 0; kt < 4; kt++) {
    w2f[kt] = wp[(size_t)(16  + wave * 4 + kt) * 64 + lane];
    uf [kt] = wp[(size_t)(192 + wave * 4 + kt) * 64 + lane];
  }
  if (wave == 7) {
    #pragma unroll
    for (int kt = 0; kt < 4; kt++)
      uf8[kt] = wp[(size_t)(192 + 32 + kt) * 64 + lane];          // U_ext tile 8
  }
  const f32x4 b2f = *(const f32x4*)(ob2  + wave * 16 + q * 4);
  const f32x4 cw  = *(const f32x4*)(cbuf + wave * 16 + q * 4);
  const f32x4 c8  = *(const f32x4*)(cbuf + 128 + q * 4);          // tile 8 const

  // ---- init: G = z@W1 + b1 ; Gd = z@decW + decb ; h1_0 -> sH1 ; store p0 ----
  const int bg = blockIdx.x * 16 + b;
  const float* zrow = wsz + (size_t)bg * 64;
  f32x4 z0a = *(const f32x4*)(zrow + q * 8);
  f32x4 z0b = *(const f32x4*)(zrow + q * 8 + 4);
  f32x4 z1a = *(const f32x4*)(zrow + 32 + q * 8);
  f32x4 z1b = *(const f32x4*)(zrow + 32 + q * 8 + 4);
  f16x8 zf0 = pack8(z0a, z0b);
  f16x8 zf1 = pack8(z1a, z1b);

  f32x4 b1v = *(const f32x4*)(ob1 + wave * 16 + q * 4);
  f32x4 G = MFMA(wp[(size_t)(wave * 2 + 0) * 64 + lane], zf0, b1v);
  G = MFMA(wp[(size_t)(wave * 2 + 1) * 64 + lane], zf1, G);
  *(uint2*)(sH1 + wr) = make_uint2(pk2(fast_tanh(G.x), fast_tanh(G.y)),
                                   pk2(fast_tanh(G.z), fast_tanh(G.w)));

  f32x4 Gd = zero4;
  float* const outp_p = dout + (size_t)bg * OT;
  float* const outp_s = dout + (size_t)TOTE + (size_t)bg * OT;
  if (wave == 7) {
    f32x4 b1d = zero4;
    if (q == 0) { b1d.x = decb[0]; b1d.y = decb[1]; }
    Gd = MFMA(wp[(size_t)48 * 64 + lane], zf0, b1d);
    Gd = MFMA(wp[(size_t)49 * 64 + lane], zf1, Gd);
    if (q == 0) { outp_p[0] = Gd.x; outp_s[0] = Gd.y; }
  }
  wg_barrier();

  #pragma unroll 1
  for (int t = 0; t < NT; ++t) {
    // ---- phase A: h2 = tanh(h1@W2 + b2) -> sH2 ----
    f16x8 p0 = *(const f16x8*)(sH1 + rd[0]);
    f16x8 p1 = *(const f16x8*)(sH1 + rd[1]);
    f16x8 p2 = *(const f16x8*)(sH1 + rd[2]);
    f16x8 p3 = *(const f16x8*)(sH1 + rd[3]);
    f32x4 a  = MFMA(w2f[0], p0, b2f);
    a  = MFMA(w2f[1], p1, a);
    f32x4 a2 = MFMA(w2f[2], p2, zero4);
    a2 = MFMA(w2f[3], p3, a2);
    f32x4 hv = a + a2;
    *(uint2*)(sH2 + wr) = make_uint2(pk2(fast_tanh(hv.x), fast_tanh(hv.y)),
                                     pk2(fast_tanh(hv.z), fast_tanh(hv.w)));
    wg_barrier();

    // ---- phase B: G += dt*(h2@U_ext + c_ext); h1' -> sH1; wave7 stores p ----
    f16x8 g0 = *(const f16x8*)(sH2 + rd[0]);
    f16x8 g1 = *(const f16x8*)(sH2 + rd[1]);
    f16x8 g2 = *(const f16x8*)(sH2 + rd[2]);
    f16x8 g3 = *(const f16x8*)(sH2 + rd[3]);
    f32x4 d  = MFMA(uf[0], g0, cw);
    d  = MFMA(uf[1], g1, d);
    f32x4 d2 = MFMA(uf[2], g2, zero4);
    d2 = MFMA(uf[3], g3, d2);
    G.x = __builtin_fmaf(dtc, d.x + d2.x, G.x);
    G.y = __builtin_fmaf(dtc, d.y + d2.y, G.y);
    G.z = __builtin_fmaf(dtc, d.z + d2.z, G.z);
    G.w = __builtin_fmaf(dtc, d.w + d2.w, G.w);
    *(uint2*)(sH1 + wr) = make_uint2(pk2(fast_tanh(G.x), fast_tanh(G.y)),
                                     pk2(fast_tanh(G.z), fast_tanh(G.w)));
    if (wave == 7) {
      f32x4 e  = MFMA(uf8[0], g0, c8);
      e  = MFMA(uf8[1], g1, e);
      f32x4 e2 = MFMA(uf8[2], g2, zero4);
      e2 = MFMA(uf8[3], g3, e2);
      Gd.x = __builtin_fmaf(dtc, e.x + e2.x, Gd.x);
      Gd.y = __builtin_fmaf(dtc, e.y + e2.y, Gd.y);
      if (q == 0) { outp_p[t + 1] = Gd.x; outp_s[t + 1] = Gd.y; }
    }
    wg_barrier();
  }
}

// ---------------------------------------------------------------------------
extern "C" void kernel_launch(void* const* d_in, const int* in_sizes, int n_in,
                              void* d_out, int out_size, void* d_ws, size_t ws_size,
                              hipStream_t stream) {
  const float* bert  = (const float*)d_in[0];
  const float* eps   = (const float*)d_in[3];
  const float* projW = (const float*)d_in[4];
  const float* projb = (const float*)d_in[5];
  const float* lng   = (const float*)d_in[6];
  const float* lnb   = (const float*)d_in[7];
  const float* lns   = (const float*)d_in[8];
  const float* denW1 = (const float*)d_in[9];
  const float* denb1 = (const float*)d_in[10];
  const float* denW2 = (const float*)d_in[11];
  const float* denb2 = (const float*)d_in[12];
  const float* odeW1 = (const float*)d_in[13];
  const float* odeb1 = (const float*)d_in[14];
  const float* odeW2 = (const float*)d_in[15];
  const float* odeb2 = (const float*)d_in[16];
  const float* odeW3 = (const float*)d_in[17];
  // d_in[18] = odeb3 (folded into cbuf), d_in[19] = decW, d_in[20] = decb
  const float* odeb3 = (const float*)d_in[18];
  const float* decW  = (const float*)d_in[19];
  const float* decb  = (const float*)d_in[20];
  float* dout = (float*)d_out;

  float* wsz  = (float*)d_ws;
  char*  wpak = (char*)d_ws + WS_WPAK;
  float* Ubuf = (float*)((char*)d_ws + WS_UBUF);
  float* cbuf = (float*)((char*)d_ws + WS_CBUF);

  compose_kernel<<<73, 256, 0, stream>>>(odeW1, odeW3, odeb3, decW, Ubuf, cbuf, dout);
  pack_kernel<<<57, 256, 0, stream>>>(odeW1, odeW2, decW, denW1, denW2, projW, Ubuf, wpak);
  prologue_kernel<<<256, 512, 0, stream>>>(bert, eps, projb, lng, lnb, lns,
                                           denb1, denb2, wpak, wsz, dout);
  ode_kernel<<<256, 512, 0, stream>>>(wsz, wpak, odeb1, cbuf, odeb2, decb, dout);
}